// Round 11
// baseline (104.714 us; speedup 1.0000x reference)
//
#include <hip/hip_runtime.h>

// 28x28 image, dim-1 persistence, card 50
#define IMG_H 28
#define IMG_W 28
#define AA 55            // 2*H-1
#define NCELL 3025       // 55*55
#define NEDGE 1512
#define NSQ 729
#define CARD 50
#define NW 24            // 1512 bits -> 24 u64 words
#define CAP 160          // LDS-resident columns (measured M <= 160 on this input)
#define BS 1024

typedef unsigned long long u64;
typedef unsigned int u32;
typedef unsigned short u16;

// ---- shared memory layout (manual union; all aliases time-disjoint) ----
#define OFF_KEYSE   0        // u64[2048] 16384          (P0-P3b)
#define OFF_KEYSS   16384    // u64[1024]  8192          (P0-P3b)
#define OFF_IP      24576    // f32[784]   3136          (P0-P1)
#define OFF_SCRE    24576    // u64[2048] 16384 ->40960  (P2 scratch; aliases dead Ip)
#define OFF_SCRS    40960    // u64[1024]  8192 ->49152  (P2 scratch)
#define OFF_RANKE   27712    // u16[1512]  3024          (P3-P3b; aliases dead scrE)
#define OFF_RANKSQ  30736    // u16[729]   1458 ->32194  (P3-P3b)
#define OFF_COL     0        // u64[CAP*24] 30720        (P4b-P4c; aliases dead keys)
#define OFF_OWNB    30720    // u64[1536] 12288 ->43008  (P4a-P4c; aliases dead ranks)
#define OFF_CANDA   0        // u64[768]   6144          (P6; aliases dead col)
#define OFF_CANDB   8192     // u64[192]   1536          (P6)
#define OFF_BND     43008    // u64[729]   5832          (P3b-P4b; aliases dead scrS)
#define OFF_EDGEF   48840    // f32[1512]  6048          (P3+)
#define OFF_SQF     54888    // f32[729]   2916 ->57804  (P3+)
#define OFF_LLIST2  57808    // u16[2*CAP]  640 ->58448  (P4)
#define OFF_CURLOW  58448    // u16[CAP]    320 ->58768  (P4)
#define OFF_LCNT    58768    // int[256]   1024 ->59792  (P4)
#define OFF_PAIRLOW 60832    // u16[729]   1458          (P3b+)
#define OFF_NONAPP  62296    // u16[736]   1472          (P4a+)
#define OFF_SCAL    63768    // float padv; int M
#define SMEM_TOTAL  63776

__device__ __forceinline__ int edgeCid(int a, int b) {
    // (a+b) odd: a odd -> [0,756); a even -> [756,1512)
    return (a & 1) ? (((a - 1) >> 1) * 28 + (b >> 1))
                   : (756 + (a >> 1) * 27 + ((b - 1) >> 1));
}

__device__ __forceinline__ u32 sortable(float f) {
    u32 fb = __float_as_uint(f);
    return (fb & 0x80000000u) ? ~fb : (fb | 0x80000000u);
}
__device__ __forceinline__ float unsortable(u32 v) {
    return __uint_as_float((v & 0x80000000u) ? (v & 0x7FFFFFFFu) : ~v);
}

__device__ __forceinline__ u64 shflx64(u64 v, int s) {
    u32 lo = __shfl_xor((u32)v, s, 64);
    u32 hi = __shfl_xor((u32)(v >> 32), s, 64);
    return ((u64)hi << 32) | lo;
}

__device__ __forceinline__ void cswapDir(u64& a, u64& b, bool up) {
    u64 mn = a < b ? a : b, mx = a < b ? b : a;
    a = up ? mn : mx; b = up ? mx : mn;
}

// generic lane-indexed stage (stride s < 64)
__device__ __forceinline__ u64 lstage(u64 v, int lane, int s, bool up) {
    u64 p = shflx64(v, s);
    bool keepmin = (up == ((lane & s) == 0));
    return keepmin ? (v < p ? v : p) : (v > p ? v : p);
}

// one shuffle stage applied to all 8 regs; upmask bit r = direction of reg r.
// LOOP-CODED on the outside (R8 lesson: full unrolling -> 100KB code -> I$ miss)
__device__ __forceinline__ void stageAll(u64 k[8], int lane, int s, u32 upmask) {
    #pragma unroll
    for (int r = 0; r < 8; ++r)
        k[r] = lstage(k[r], lane, s, ((upmask >> r) & 1u) != 0u);
}
__device__ __forceinline__ void cswapPairs(u64 k[8], int d, u32 upmask) {
    #pragma unroll
    for (int r = 0; r < 8; ++r)
        if (!(r & d)) cswapDir(k[r], k[r | d], ((upmask >> r) & 1u) != 0u);
}

// finishing merge of a bitonic 512-chunk in regs (strides 256..1), dir=up.
// Element i = r*64 + lane. Masks verified against R8's unrolled version.
__device__ __forceinline__ void mergeReg512L(u64 k[8], int lane, bool up) {
    cswapPairs(k, 4, up ? 0x0Fu : 0x00u);
    cswapPairs(k, 2, up ? 0x33u : 0x00u);
    cswapPairs(k, 1, up ? 0x55u : 0x00u);
    const u32 dm = up ? 0xFFu : 0x00u;
    for (int s = 32; s; s >>= 1) stageAll(k, lane, s, dm);
}

// full bitonic sort of 512 elements in one wave, 0 barriers, loop-coded.
__device__ __forceinline__ void sortReg512L(u64 k[8], int lane, bool finalUp) {
    for (int size = 2; size <= 32; size <<= 1) {
        const u32 dm = ((lane & size) == 0) ? 0xFFu : 0x00u;
        for (int s = size >> 1; s; s >>= 1) stageAll(k, lane, s, dm);
    }
    for (int s = 32; s; s >>= 1) stageAll(k, lane, s, 0x55u);      // size 64
    cswapPairs(k, 1, 0x11u);                                       // size 128
    for (int s = 32; s; s >>= 1) stageAll(k, lane, s, 0x33u);
    cswapPairs(k, 2, 0x03u);                                       // size 256
    cswapPairs(k, 1, 0x05u);
    for (int s = 32; s; s >>= 1) stageAll(k, lane, s, 0x0Fu);
    mergeReg512L(k, lane, finalUp);                                // size 512
}

// full ascending bitonic sort of 64 elements (1 reg/lane), loop-coded
__device__ __forceinline__ u64 sort64(u64 v, int lane) {
    for (int size = 2; size <= 32; size <<= 1)
        for (int s = size >> 1; s; s >>= 1)
            v = lstage(v, lane, s, (lane & size) == 0);
    for (int s = 32; s; s >>= 1)
        v = lstage(v, lane, s, true);
    return v;
}
// merge two ascending 64-lists, keep smallest 64 (exact), ascending result
__device__ __forceinline__ u64 merge64(u64 a, u64 b, int lane) {
    u64 br = shflx64(b, 63);            // reverse
    u64 m = a < br ? a : br;            // bitonic lower half
    for (int s = 32; s; s >>= 1)
        m = lstage(m, lane, s, true);
    return m;
}

// XOR the owner's column into w. bit63=0 -> apparent (4x12-bit edge ranks
// inline); bit63=1 -> settled column slot.
__device__ __forceinline__ void xorOwner(u64 o, u64& w, int lane, const u64* col) {
    if (!(o >> 63)) {
        #pragma unroll
        for (int q = 0; q < 4; ++q) {
            int rr = (int)((o >> (12 * q)) & 0xFFFull);
            if ((rr >> 6) == lane) w ^= 1ull << (rr & 63);
        }
    } else {
        int s = (int)(o & 0xFFFFull);
        if (lane < NW) w ^= col[s * NW + lane];
    }
}

// highest set bit position across the wave's 64xu64 bitset (lane i = word i)
__device__ __forceinline__ int findLow(u64 w, int lane) {
    u64 mask = __ballot(w != 0ull);
    if (mask == 0ull) return 0xFFFE;                 // dead
    int L = 63 - __builtin_clzll(mask);
    int cand = (lane << 6) + 63 - __builtin_clzll(w | 1ull);  // valid where w!=0
    return __builtin_amdgcn_readlane(cand, L);
}

__global__ __launch_bounds__(BS) void cubical_kernel(const float* __restrict__ I,
                                                     const float* __restrict__ p,
                                                     float* __restrict__ out) {
    __shared__ __align__(16) char smem[SMEM_TOTAL];
    u64*    keysE   = (u64*)(smem + OFF_KEYSE);
    u64*    keysS   = (u64*)(smem + OFF_KEYSS);
    float*  Ip      = (float*)(smem + OFF_IP);
    u64*    scrE    = (u64*)(smem + OFF_SCRE);
    u64*    scrS    = (u64*)(smem + OFF_SCRS);
    u16*    rankE   = (u16*)(smem + OFF_RANKE);
    u16*    rankSq  = (u16*)(smem + OFF_RANKSQ);
    u64*    col     = (u64*)(smem + OFF_COL);      // [CAP][NW]
    u64*    ownerBnd= (u64*)(smem + OFF_OWNB);     // [1536]
    u64*    candA   = (u64*)(smem + OFF_CANDA);    // [768]
    u64*    candB   = (u64*)(smem + OFF_CANDB);    // [192]
    u64*    bnd     = (u64*)(smem + OFF_BND);
    float*  edgeFr  = (float*)(smem + OFF_EDGEF);
    float*  sqF     = (float*)(smem + OFF_SQF);
    u16*    lList2  = (u16*)(smem + OFF_LLIST2);   // [2][CAP]
    u16*    curLow  = (u16*)(smem + OFF_CURLOW);
    int*    lCntArr = (int*)(smem + OFF_LCNT);     // [256]
    u16*    pairLow = (u16*)(smem + OFF_PAIRLOW);
    u16*    nonapp  = (u16*)(smem + OFF_NONAPP);
    float*  padvP   = (float*)(smem + OFF_SCAL);
    int*    Mp      = (int*)(smem + OFF_SCAL + 4);

    const int tid = threadIdx.x;
    const int wave = tid >> 6, lane = tid & 63;

    // ---- P0: Ip = I.p ; pads ----
    const float p0 = p[0], p1 = p[1];
    for (int i = tid; i < IMG_H * IMG_W; i += BS) {
        float v = I[2 * i] * p0 + I[2 * i + 1] * p1;
        Ip[i] = v;
        if (i == 0) *padvP = v;
    }
    for (int i = 1512 + tid; i < 2048; i += BS) keysE[i] = ~0ull;
    for (int i = 729 + tid; i < 1024; i += BS) keysS[i] = ~0ull;
    __syncthreads();

    // ---- P1: F + sort keys for edges & squares ----
    for (int idx = tid; idx < NCELL; idx += BS) {
        int a = idx / AA, b = idx % AA;
        int da = a & 1, db = b & 1;
        int dim = da + db;
        if (dim == 0) continue;
        int r0, r1, c0, c1;
        if (da) { r0 = r1 = (a - 1) >> 1; }
        else    { r1 = a >> 1; r0 = (a == 0) ? r1 : r1 - 1; }
        if (db) { c0 = c1 = (b - 1) >> 1; }
        else    { c1 = b >> 1; c0 = (b == 0) ? c1 : c1 - 1; }
        float best = Ip[r0 * IMG_W + c0];
        best = fminf(best, Ip[r0 * IMG_W + c1]);
        best = fminf(best, Ip[r1 * IMG_W + c0]);
        best = fminf(best, Ip[r1 * IMG_W + c1]);
        u64 key = ((u64)sortable(best) << 12) | (u32)idx;
        if (dim == 1) keysE[edgeCid(a, b)] = key;
        else          keysS[((a - 1) >> 1) * 27 + ((b - 1) >> 1)] = key;
    }
    __syncthreads();

    // ---- P2: register-resident bitonic sorts, 4 barriers (R8 structure,
    // loop-coded to keep code small). Edges: waves 0-3; squares: waves 4-5.
    {
        const bool isE = (wave < 4);
        const bool isS = (wave >= 4 && wave < 6);
        const int gE = wave, gS = wave - 4;
        u64 k[8];
        if (isE | isS) {
            u64* src = isE ? (keysE + gE * 512) : (keysS + gS * 512);
            u64* dst = isE ? (scrE + gE * 512) : (scrS + gS * 512);
            bool fup = isE ? ((gE & 1) == 0) : ((gS & 1) == 0);
            #pragma unroll
            for (int r = 0; r < 8; ++r) k[r] = src[r * 64 + lane];
            sortReg512L(k, lane, fup);
            #pragma unroll
            for (int r = 0; r < 8; ++r) dst[r * 64 + lane] = k[r];
        }
        __syncthreads();   // B1: scratch visible
        if (isE | isS) {
            // size-1024 merge: partner chunk via scratch, then finish in regs
            u64* ppt = isE ? (scrE + (gE ^ 1) * 512) : (scrS + (gS ^ 1) * 512);
            bool mup = isE ? (gE < 2) : true;
            bool km  = isE ? (mup == ((gE & 1) == 0)) : (gS == 0);
            #pragma unroll
            for (int r = 0; r < 8; ++r) {
                u64 pv = ppt[r * 64 + lane];
                k[r] = km ? (k[r] < pv ? k[r] : pv) : (k[r] > pv ? k[r] : pv);
            }
            mergeReg512L(k, lane, mup);
            u64* dst = isE ? (keysE + gE * 512) : (keysS + gS * 512);
            #pragma unroll
            for (int r = 0; r < 8; ++r) dst[r * 64 + lane] = k[r];  // squares FINAL
        }
        __syncthreads();   // B2: keysE (post-1024) / keysS final visible
        if (isE) {
            // size 2048, stride 1024 (cross-wave via keysE)
            const bool km = ((gE & 2) == 0);
            #pragma unroll
            for (int r = 0; r < 8; ++r) {
                u64 pv = keysE[(gE ^ 2) * 512 + r * 64 + lane];
                k[r] = km ? (k[r] < pv ? k[r] : pv) : (k[r] > pv ? k[r] : pv);
            }
            #pragma unroll
            for (int r = 0; r < 8; ++r) scrE[gE * 512 + r * 64 + lane] = k[r];
        }
        __syncthreads();   // B3: scratch (post-stride-1024) visible
        if (isE) {
            // stride 512 (cross-wave), then finish in regs -> all ascending
            const bool km = ((gE & 1) == 0);
            #pragma unroll
            for (int r = 0; r < 8; ++r) {
                u64 pv = scrE[(gE ^ 1) * 512 + r * 64 + lane];
                k[r] = km ? (k[r] < pv ? k[r] : pv) : (k[r] > pv ? k[r] : pv);
            }
            mergeReg512L(k, lane, true);
            #pragma unroll
            for (int r = 0; r < 8; ++r) keysE[gE * 512 + r * 64 + lane] = k[r];  // FINAL
        }
        __syncthreads();   // B4: sorted keys visible to P3
    }

    // ---- P3: rank lookups + F-by-rank ----
    for (int r = tid; r < NEDGE; r += BS) {
        u64 k = keysE[r];
        int idx = (int)(k & 0xFFFull);
        int a = idx / AA, b = idx % AA;
        rankE[edgeCid(a, b)] = (u16)r;
        edgeFr[r] = unsortable((u32)(k >> 12));
    }
    for (int r = tid; r < NSQ; r += BS) {
        u64 k = keysS[r];
        int idx = (int)(k & 0xFFFull);
        int a = idx / AA, b = idx % AA;
        rankSq[((a - 1) >> 1) * 27 + ((b - 1) >> 1)] = (u16)r;
        sqF[r] = unsortable((u32)(k >> 12));
    }
    __syncthreads();

    // ---- P3b: boundary ranks + apparent-pair detection ----
    // pairLow: apparent -> 0x8000|low ; pending -> 0xFFFF.
    for (int j = tid; j < NSQ; j += BS) {
        int sidx = (int)(keysS[j] & 0xFFFull);
        int a = sidx / AA, b = sidx % AA;          // both odd
        int ec[4] = { sidx - AA, sidx + AA, sidx - 1, sidx + 1 };
        int er[4];
        er[0] = rankE[edgeCid(a - 1, b)];
        er[1] = rankE[edgeCid(a + 1, b)];
        er[2] = rankE[edgeCid(a, b - 1)];
        er[3] = rankE[edgeCid(a, b + 1)];
        bnd[j] = (u64)er[0] | ((u64)er[1] << 16) | ((u64)er[2] << 32) | ((u64)er[3] << 48);
        int bq = 0;
        if (er[1] > er[bq]) bq = 1;
        if (er[2] > er[bq]) bq = 2;
        if (er[3] > er[bq]) bq = 3;
        int ecell = ec[bq];
        int x = ecell / AA, y = ecell % AA;
        u32 rmin = 0xFFFFFFFFu;
        if (x & 1) {
            if (y >= 2)  rmin = rankSq[((x - 1) >> 1) * 27 + ((y - 2) >> 1)];
            if (y <= 52) { u32 r2 = rankSq[((x - 1) >> 1) * 27 + (y >> 1)]; rmin = min(rmin, r2); }
        } else {
            if (x >= 2)  rmin = rankSq[((x - 2) >> 1) * 27 + ((y - 1) >> 1)];
            if (x <= 52) { u32 r2 = rankSq[(x >> 1) * 27 + ((y - 1) >> 1)]; rmin = min(rmin, r2); }
        }
        pairLow[j] = (rmin == (u32)j) ? (u16)(0x8000u | er[bq]) : (u16)0xFFFFu;
    }
    __syncthreads();   // keys/rank region dead from here

    // ---- P4a: fused owner table init + apparent installs + compact pending ----
    for (int i = tid; i < 1536; i += BS) ownerBnd[i] = ~0ull;
    __syncthreads();
    for (int j = tid; j < NSQ; j += BS) {
        u16 pl = pairLow[j];
        if (pl != 0xFFFFu) {
            u64 bd = bnd[j];
            u64 e = (bd & 0xFFFull) | (((bd >> 16) & 0xFFFull) << 12)
                  | (((bd >> 32) & 0xFFFull) << 24) | (((bd >> 48) & 0xFFFull) << 36);
            ownerBnd[pl & 0x7FFF] = e;   // unique per low; bit63=0 < settled encs
        }
    }
    if (tid < 64) {
        int cnt = 0;
        for (int base = 0; base < NSQ; base += 64) {
            int j = base + lane;
            bool f = (j < NSQ) && (pairLow[j] == 0xFFFFu);
            u64 m = __ballot(f);
            int pfx = __popcll(m & ((1ull << lane) - 1ull));
            if (f) nonapp[cnt + pfx] = (u16)j;
            cnt += __popcll(m);
        }
        if (lane == 0) *Mp = (cnt > CAP) ? CAP : cnt;
    }
    __syncthreads();
    const int M = *Mp;

    // ---- P4b: init columns + lows + round-0 work list + per-round counters ----
    for (int idx = tid; idx < M * NW; idx += BS) {
        int slot = idx / NW, w = idx - slot * NW;
        u64 bd = bnd[nonapp[slot]];
        u64 x = 0ull;
        #pragma unroll
        for (int q = 0; q < 4; ++q) {
            int rr = (int)((bd >> (16 * q)) & 0xFFFFull);
            if ((rr >> 6) == w) x ^= 1ull << (rr & 63);
        }
        col[idx] = x;
    }
    if (tid < 256) lCntArr[tid] = 0;
    if (tid < M) {
        u64 bd = bnd[nonapp[tid]];
        int mx = 0;
        #pragma unroll
        for (int q = 0; q < 4; ++q) {
            int rr = (int)((bd >> (16 * q)) & 0xFFFFull);
            if (rr > mx) mx = rr;
        }
        curLow[tid] = (u16)mx;
        lList2[tid] = (u16)tid;
    }
    if (tid == 0) lCntArr[0] = M;
    __syncthreads();

    // ---- P4c: chase-and-claim, 1 barrier/round (R8/R9-verified). Smaller-
    // into-larger only: at low L with owner o < myEnc, XOR through and keep
    // chasing; at o >= myEnc: publish col, fence, CAS-min claim (evictor
    // appends any displaced settled victim to the next round's list).
    // Race-losers XOR through the new smaller owner inline.
    {
        const int nWaves = BS / 64;
        for (int round = 0; round < 255; ++round) {
            const int nL = lCntArr[round];            // stable post-barrier
            if (nL == 0) break;
            const u16* inL = lList2 + (round & 1) * CAP;
            u16* outL = lList2 + ((round + 1) & 1) * CAP;
            int* outC = lCntArr + (round + 1);        // pre-zeroed
            for (int li = wave; li < nL; li += nWaves) {
                int slot = (int)inL[li];
                const u64 myEnc = (1ull << 63) | (u64)slot;
                u64 w = (lane < NW) ? col[slot * NW + lane] : 0ull;
                int low = (int)curLow[slot];
                while (low != 0xFFFE) {
                    u64 o = *(volatile u64*)&ownerBnd[low];
                    if (o < myEnc) {
                        xorOwner(o, w, lane, col);
                        low = findLow(w, lane);
                    } else {
                        if (lane < NW) col[slot * NW + lane] = w;
                        __threadfence_block();
                        u64 got = 0;
                        if (lane == 0) {
                            u64 cur = *(volatile u64*)&ownerBnd[low];
                            while (myEnc < cur) {
                                u64 prev = atomicCAS(&ownerBnd[low], cur, myEnc);
                                if (prev == cur) {
                                    if (cur != ~0ull) {        // evicted settled col
                                        int ix = atomicAdd(outC, 1);
                                        outL[ix] = (u16)(cur & 0xFFFFull);
                                    }
                                    break;
                                }
                                cur = prev;
                            }
                            got = cur;
                        }
                        u32 glo = __builtin_amdgcn_readlane((u32)got, 0);
                        u32 ghi = __builtin_amdgcn_readlane((u32)(got >> 32), 0);
                        got = ((u64)ghi << 32) | glo;
                        if (got < myEnc) {           // raced & lost: reduce through
                            xorOwner(got, w, lane, col);
                            low = findLow(w, lane);
                        } else break;                // rested
                    }
                }
                if (lane == 0) curLow[slot] = (u16)low;
                if (lane < NW) col[slot * NW + lane] = w;
            }
            __syncthreads();
        }
    }
    // publish pairs for non-apparent squares
    if (tid < M) {
        u16 cl = curLow[tid];
        pairLow[nonapp[tid]] = (cl == 0xFFFEu) ? (u16)0xFFFDu : cl;
    }
    __syncthreads();

    // ---- P5+P6+P7 fused: packed keys + exact 64-wide tournament (3 barriers) ----
    // key = ~((f64_bits(pr) & ~0xFFF) | j): distinct pr (f32 differences) are
    // >=2^27 d-ulps apart, so low 12 bits carry j; ascending = descending
    // (pr, j) = argsort(pers)[::-1]. 12 chunks of 64 -> sort64 each -> merge
    // tree 12->6->3->1 keeping exact smallest-64 at every level.
    {
        if (wave < 12) {
            int i = wave * 64 + lane;
            u64 key = ~0ull;
            if (i < NSQ) {
                int pl = (int)pairLow[i];
                if (pl != 0xFFFD && pl != 0xFFFF) {
                    int low = pl & 0x7FFF;
                    double pr = (double)sqF[i] - (double)edgeFr[low];
                    if (pr > 0.0) {
                        u64 bits = (u64)__double_as_longlong(pr);
                        key = ~((bits & ~0xFFFull) | (u64)(u32)i);
                    }
                }
            }
            candA[wave * 64 + lane] = sort64(key, lane);
        }
        __syncthreads();
        if (wave < 6) {
            u64 a = candA[(2 * wave) * 64 + lane];
            u64 b = candA[(2 * wave + 1) * 64 + lane];
            candB[wave * 64 + lane] = merge64(a, b, lane);
        }
        __syncthreads();
        if (wave < 3) {
            u64 a = candB[(2 * wave) * 64 + lane];
            u64 b = candB[(2 * wave + 1) * 64 + lane];
            candA[wave * 64 + lane] = merge64(a, b, lane);
        }
        __syncthreads();
        if (wave == 0) {
            u64 a = candA[lane], b = candA[64 + lane], c = candA[128 + lane];
            u64 f = merge64(merge64(a, b, lane), c, lane);
            if (lane < CARD) {
                float bv, dv;
                if (f != ~0ull) {
                    u64 kb = ~f;
                    int j = (int)(kb & 0xFFFull);
                    int low = (int)pairLow[j] & 0x7FFF;
                    bv = edgeFr[low];
                    dv = sqF[j];
                } else {
                    bv = *padvP; dv = *padvP;    // pad rows -> Ip[0,0]
                }
                out[2 * lane]     = bv;
                out[2 * lane + 1] = dv;
            }
        }
    }
}

extern "C" void kernel_launch(void* const* d_in, const int* in_sizes, int n_in,
                              void* d_out, int out_size, void* d_ws, size_t ws_size,
                              hipStream_t stream) {
    const float* I = (const float*)d_in[0];   // [28,28,2] float32
    const float* p = (const float*)d_in[1];   // [2,1] float32
    float* out = (float*)d_out;               // [50,2] float32 flat
    hipLaunchKernelGGL(cubical_kernel, dim3(1), dim3(BS), 0, stream, I, p, out);
}

// Round 12
// 103.984 us; speedup vs baseline: 1.0070x; 1.0070x over previous
//
#include <hip/hip_runtime.h>

// 28x28 image, dim-1 persistence, card 50
#define IMG_H 28
#define IMG_W 28
#define AA 55            // 2*H-1
#define NCELL 3025       // 55*55
#define NEDGE 1512
#define NSQ 729
#define CARD 50
#define NW 24            // 1512 bits -> 24 u64 words
#define CAP 160          // LDS-resident columns (measured M <= 160 on this input)
#define BS 1024

typedef unsigned long long u64;
typedef unsigned int u32;
typedef unsigned short u16;

// ---- shared memory layout (manual union; all aliases time-disjoint) ----
#define OFF_KEYSE   0        // u64[2048] 16384          (P0-P3b)
#define OFF_KEYSS   16384    // u64[1024]  8192          (P0-P3b)
#define OFF_IP      24576    // f32[784]   3136          (P0-P1)
#define OFF_RANKE   27712    // u16[1512]  3024          (P3-P3b)
#define OFF_RANKSQ  30736    // u16[729]   1458 ->32194  (P3-P3b)
#define OFF_COL     0        // u64[CAP*24] 30720        (P4b-P4c; aliases dead keys)
#define OFF_OWNB    30720    // u64[1536] 12288 ->43008  (P4a-P4c; aliases dead ranks)
#define OFF_CANDA   0        // u64[768]   6144          (P6; aliases dead col)
#define OFF_CANDB   8192     // u64[192]   1536          (P6)
#define OFF_BND     43008    // u64[729]   5832          (P3b-P4b)
#define OFF_EDGEF   48840    // f32[1512]  6048          (P3+)
#define OFF_SQF     54888    // f32[729]   2916 ->57804  (P3+)
#define OFF_LLIST2  57808    // u16[2*CAP]  640 ->58448  (P4)
#define OFF_CURLOW  58448    // u16[CAP]    320 ->58768  (P4)
#define OFF_LCNT    58768    // int[256]   1024 ->59792  (P4)
#define OFF_PAIRLOW 60832    // u16[729]   1458          (P3b+)
#define OFF_NONAPP  62296    // u16[736]   1472          (P4a+)
#define OFF_SCAL    63768    // float padv; int M
#define SMEM_TOTAL  63776

__device__ __forceinline__ int edgeCid(int a, int b) {
    // (a+b) odd: a odd -> [0,756); a even -> [756,1512)
    return (a & 1) ? (((a - 1) >> 1) * 28 + (b >> 1))
                   : (756 + (a >> 1) * 27 + ((b - 1) >> 1));
}

__device__ __forceinline__ u32 sortable(float f) {
    u32 fb = __float_as_uint(f);
    return (fb & 0x80000000u) ? ~fb : (fb | 0x80000000u);
}
__device__ __forceinline__ float unsortable(u32 v) {
    return __uint_as_float((v & 0x80000000u) ? (v & 0x7FFFFFFFu) : ~v);
}

__device__ __forceinline__ u64 shflx64(u64 v, int s) {
    u32 lo = __shfl_xor((u32)v, s, 64);
    u32 hi = __shfl_xor((u32)(v >> 32), s, 64);
    return ((u64)hi << 32) | lo;
}

// one cross-lane bitonic stage (stride s<64) on register v at element index i
__device__ __forceinline__ u64 bstage(u64 v, int i, int s, int size) {
    u64 p = shflx64(v, s);
    bool keepmin = (((i & size) == 0) == ((i & s) == 0));
    return keepmin ? (v < p ? v : p) : (v > p ? v : p);
}

// session A: sizes 2..64, all strides, on a 128-chunk (r0@i0, r1@i0+64)
__device__ __forceinline__ void sessA(u64& r0, u64& r1, int i0) {
    for (int size = 2; size <= 64; size <<= 1)
        for (int s = size >> 1; s; s >>= 1) {
            r0 = bstage(r0, i0, s, size);
            r1 = bstage(r1, i0 + 64, s, size);
        }
}
// session B: one size>=128, strides 64..1 (asc uniform over the chunk)
__device__ __forceinline__ void sessB(u64& r0, u64& r1, int i0, int size) {
    bool asc = ((i0 & size) == 0);
    { u64 mn = r0 < r1 ? r0 : r1, mx = r0 < r1 ? r1 : r0;
      r0 = asc ? mn : mx; r1 = asc ? mx : mn; }
    for (int s = 32; s; s >>= 1) {
        bool keep = (asc == ((i0 & s) == 0));
        u64 p0 = shflx64(r0, s);
        r0 = keep ? (r0 < p0 ? r0 : p0) : (r0 > p0 ? r0 : p0);
        u64 p1 = shflx64(r1, s);
        r1 = keep ? (r1 < p1 ? r1 : p1) : (r1 > p1 ? r1 : p1);
    }
}

// generic lane-indexed stage for the P6 helpers
__device__ __forceinline__ u64 lstage(u64 v, int lane, int s, bool up) {
    u64 p = shflx64(v, s);
    bool keepmin = (up == ((lane & s) == 0));
    return keepmin ? (v < p ? v : p) : (v > p ? v : p);
}

// full ascending bitonic sort of 64 elements (1 reg/lane), loop-coded
__device__ __forceinline__ u64 sort64(u64 v, int lane) {
    for (int size = 2; size <= 32; size <<= 1)
        for (int s = size >> 1; s; s >>= 1)
            v = lstage(v, lane, s, (lane & size) == 0);
    for (int s = 32; s; s >>= 1)
        v = lstage(v, lane, s, true);
    return v;
}
// merge two ascending 64-lists, keep smallest 64 (exact), ascending result
__device__ __forceinline__ u64 merge64(u64 a, u64 b, int lane) {
    u64 br = shflx64(b, 63);            // reverse
    u64 m = a < br ? a : br;            // bitonic lower half
    for (int s = 32; s; s >>= 1)
        m = lstage(m, lane, s, true);
    return m;
}

// XOR the owner's column into w (dual-chase: word index = sublane).
// bit63=0 -> apparent (4x12-bit edge ranks inline); bit63=1 -> settled slot.
__device__ __forceinline__ void xorOwnerH(u64 o, u64& w, int sub, const u64* col) {
    if (!(o >> 63)) {
        #pragma unroll
        for (int q = 0; q < 4; ++q) {
            int rr = (int)((o >> (12 * q)) & 0xFFFull);
            if ((rr >> 6) == sub) w ^= 1ull << (rr & 63);
        }
    } else {
        int s = (int)(o & 0xFFFFull);
        if (sub < NW) w ^= col[s * NW + sub];
    }
}

__global__ __launch_bounds__(BS) void cubical_kernel(const float* __restrict__ I,
                                                     const float* __restrict__ p,
                                                     float* __restrict__ out) {
    __shared__ __align__(16) char smem[SMEM_TOTAL];
    u64*    keysE   = (u64*)(smem + OFF_KEYSE);
    u64*    keysS   = (u64*)(smem + OFF_KEYSS);
    float*  Ip      = (float*)(smem + OFF_IP);
    u16*    rankE   = (u16*)(smem + OFF_RANKE);
    u16*    rankSq  = (u16*)(smem + OFF_RANKSQ);
    u64*    col     = (u64*)(smem + OFF_COL);      // [CAP][NW]
    u64*    ownerBnd= (u64*)(smem + OFF_OWNB);     // [1536]
    u64*    candA   = (u64*)(smem + OFF_CANDA);    // [768]
    u64*    candB   = (u64*)(smem + OFF_CANDB);    // [192]
    u64*    bnd     = (u64*)(smem + OFF_BND);
    float*  edgeFr  = (float*)(smem + OFF_EDGEF);
    float*  sqF     = (float*)(smem + OFF_SQF);
    u16*    lList2  = (u16*)(smem + OFF_LLIST2);   // [2][CAP]
    u16*    curLow  = (u16*)(smem + OFF_CURLOW);
    int*    lCntArr = (int*)(smem + OFF_LCNT);     // [256]
    u16*    pairLow = (u16*)(smem + OFF_PAIRLOW);
    u16*    nonapp  = (u16*)(smem + OFF_NONAPP);
    float*  padvP   = (float*)(smem + OFF_SCAL);
    int*    Mp      = (int*)(smem + OFF_SCAL + 4);

    const int tid = threadIdx.x;
    const int wave = tid >> 6, lane = tid & 63;

    // ---- P0: Ip = I.p ; pads ----
    const float p0 = p[0], p1 = p[1];
    for (int i = tid; i < IMG_H * IMG_W; i += BS) {
        float v = I[2 * i] * p0 + I[2 * i + 1] * p1;
        Ip[i] = v;
        if (i == 0) *padvP = v;
    }
    for (int i = 1512 + tid; i < 2048; i += BS) keysE[i] = ~0ull;
    for (int i = 729 + tid; i < 1024; i += BS) keysS[i] = ~0ull;
    __syncthreads();

    // ---- P1: F + sort keys for edges & squares ----
    for (int idx = tid; idx < NCELL; idx += BS) {
        int a = idx / AA, b = idx % AA;
        int da = a & 1, db = b & 1;
        int dim = da + db;
        if (dim == 0) continue;
        int r0, r1, c0, c1;
        if (da) { r0 = r1 = (a - 1) >> 1; }
        else    { r1 = a >> 1; r0 = (a == 0) ? r1 : r1 - 1; }
        if (db) { c0 = c1 = (b - 1) >> 1; }
        else    { c1 = b >> 1; c0 = (b == 0) ? c1 : c1 - 1; }
        float best = Ip[r0 * IMG_W + c0];
        best = fminf(best, Ip[r0 * IMG_W + c1]);
        best = fminf(best, Ip[r1 * IMG_W + c0]);
        best = fminf(best, Ip[r1 * IMG_W + c1]);
        u64 key = ((u64)sortable(best) << 12) | (u32)idx;
        if (dim == 1) keysE[edgeCid(a, b)] = key;
        else          keysS[((a - 1) >> 1) * 27 + ((b - 1) >> 1)] = key;
    }
    __syncthreads();

    // ---- P2: bitonic sorts with in-wave register sessions (R9-verified;
    // 16 barriers, 16 waves active — beats 4-barrier/6-wave variant, R10) ----
    {
        const int eB = wave * 128 + lane;      // edge chunk element i0 (16 waves)
        const int sB = wave * 128 + lane;      // square chunk (waves 0-7)
        const bool hasS = (wave < 8);
        {
            u64 a = keysE[eB], b = keysE[eB + 64];
            sessA(a, b, eB);
            keysE[eB] = a; keysE[eB + 64] = b;
            if (hasS) {
                u64 c = keysS[sB], d = keysS[sB + 64];
                sessA(c, d, sB);
                keysS[sB] = c; keysS[sB + 64] = d;
            }
        }
        __syncthreads();
        for (int size = 128; size <= 2048; size <<= 1) {
            for (int stride = size >> 1; stride >= 128; stride >>= 1) {
                for (int i = tid; i < 2048; i += BS) {
                    int jx = i ^ stride;
                    if (jx > i) {
                        bool up = ((i & size) == 0);
                        u64 x = keysE[i], y = keysE[jx];
                        if (up ? (x > y) : (x < y)) { keysE[i] = y; keysE[jx] = x; }
                    }
                }
                if (size <= 1024) {
                    for (int i = tid; i < 1024; i += BS) {
                        int jx = i ^ stride;
                        if (jx > i) {
                            bool up = ((i & size) == 0);
                            u64 x = keysS[i], y = keysS[jx];
                            if (up ? (x > y) : (x < y)) { keysS[i] = y; keysS[jx] = x; }
                        }
                    }
                }
                __syncthreads();
            }
            {
                u64 a = keysE[eB], b = keysE[eB + 64];
                sessB(a, b, eB, size);
                keysE[eB] = a; keysE[eB + 64] = b;
                if (hasS && size <= 1024) {
                    u64 c = keysS[sB], d = keysS[sB + 64];
                    sessB(c, d, sB, size);
                    keysS[sB] = c; keysS[sB + 64] = d;
                }
            }
            __syncthreads();
        }
    }

    // ---- P3: rank lookups + F-by-rank ----
    for (int r = tid; r < NEDGE; r += BS) {
        u64 k = keysE[r];
        int idx = (int)(k & 0xFFFull);
        int a = idx / AA, b = idx % AA;
        rankE[edgeCid(a, b)] = (u16)r;
        edgeFr[r] = unsortable((u32)(k >> 12));
    }
    for (int r = tid; r < NSQ; r += BS) {
        u64 k = keysS[r];
        int idx = (int)(k & 0xFFFull);
        int a = idx / AA, b = idx % AA;
        rankSq[((a - 1) >> 1) * 27 + ((b - 1) >> 1)] = (u16)r;
        sqF[r] = unsortable((u32)(k >> 12));
    }
    __syncthreads();

    // ---- P3b: boundary ranks + apparent-pair detection ----
    // pairLow: apparent -> 0x8000|low ; pending -> 0xFFFF.
    for (int j = tid; j < NSQ; j += BS) {
        int sidx = (int)(keysS[j] & 0xFFFull);
        int a = sidx / AA, b = sidx % AA;          // both odd
        int ec[4] = { sidx - AA, sidx + AA, sidx - 1, sidx + 1 };
        int er[4];
        er[0] = rankE[edgeCid(a - 1, b)];
        er[1] = rankE[edgeCid(a + 1, b)];
        er[2] = rankE[edgeCid(a, b - 1)];
        er[3] = rankE[edgeCid(a, b + 1)];
        bnd[j] = (u64)er[0] | ((u64)er[1] << 16) | ((u64)er[2] << 32) | ((u64)er[3] << 48);
        int bq = 0;
        if (er[1] > er[bq]) bq = 1;
        if (er[2] > er[bq]) bq = 2;
        if (er[3] > er[bq]) bq = 3;
        int ecell = ec[bq];
        int x = ecell / AA, y = ecell % AA;
        u32 rmin = 0xFFFFFFFFu;
        if (x & 1) {
            if (y >= 2)  rmin = rankSq[((x - 1) >> 1) * 27 + ((y - 2) >> 1)];
            if (y <= 52) { u32 r2 = rankSq[((x - 1) >> 1) * 27 + (y >> 1)]; rmin = min(rmin, r2); }
        } else {
            if (x >= 2)  rmin = rankSq[((x - 2) >> 1) * 27 + ((y - 1) >> 1)];
            if (x <= 52) { u32 r2 = rankSq[(x >> 1) * 27 + ((y - 1) >> 1)]; rmin = min(rmin, r2); }
        }
        pairLow[j] = (rmin == (u32)j) ? (u16)(0x8000u | er[bq]) : (u16)0xFFFFu;
    }
    __syncthreads();   // keys/rank region dead from here

    // ---- P4a: fused owner table init + apparent installs + compact pending ----
    for (int i = tid; i < 1536; i += BS) ownerBnd[i] = ~0ull;
    __syncthreads();
    for (int j = tid; j < NSQ; j += BS) {
        u16 pl = pairLow[j];
        if (pl != 0xFFFFu) {
            u64 bd = bnd[j];
            u64 e = (bd & 0xFFFull) | (((bd >> 16) & 0xFFFull) << 12)
                  | (((bd >> 32) & 0xFFFull) << 24) | (((bd >> 48) & 0xFFFull) << 36);
            ownerBnd[pl & 0x7FFF] = e;   // unique per low; bit63=0 < settled encs
        }
    }
    if (tid < 64) {
        int cnt = 0;
        for (int base = 0; base < NSQ; base += 64) {
            int j = base + lane;
            bool f = (j < NSQ) && (pairLow[j] == 0xFFFFu);
            u64 m = __ballot(f);
            int pfx = __popcll(m & ((1ull << lane) - 1ull));
            if (f) nonapp[cnt + pfx] = (u16)j;
            cnt += __popcll(m);
        }
        if (lane == 0) *Mp = (cnt > CAP) ? CAP : cnt;
    }
    __syncthreads();
    const int M = *Mp;

    // ---- P4b: init columns + lows + round-0 work list + per-round counters ----
    for (int idx = tid; idx < M * NW; idx += BS) {
        int slot = idx / NW, w = idx - slot * NW;
        u64 bd = bnd[nonapp[slot]];
        u64 x = 0ull;
        #pragma unroll
        for (int q = 0; q < 4; ++q) {
            int rr = (int)((bd >> (16 * q)) & 0xFFFFull);
            if ((rr >> 6) == w) x ^= 1ull << (rr & 63);
        }
        col[idx] = x;
    }
    if (tid < 256) lCntArr[tid] = 0;
    if (tid < M) {
        u64 bd = bnd[nonapp[tid]];
        int mx = 0;
        #pragma unroll
        for (int q = 0; q < 4; ++q) {
            int rr = (int)((bd >> (16 * q)) & 0xFFFFull);
            if (rr > mx) mx = rr;
        }
        curLow[tid] = (u16)mx;
        lList2[tid] = (u16)tid;
    }
    if (tid == 0) lCntArr[0] = M;
    __syncthreads();

    // ---- P4c: DUAL-CHASE chase-and-claim, 1 barrier/round. Two independent
    // chases per wave: half h = lanes [32h,32h+32), sublane = bitset word.
    // Same protocol as R9 (verified): smaller-into-larger XOR-through; at
    // o >= myEnc publish col + fence + CAS-min claim; evictor appends victim;
    // race-losers XOR through the new smaller owner inline.
    {
        const int h = lane >> 5;           // half id (0/1)
        const int sub = lane & 31;         // word index when < NW
        for (int round = 0; round < 255; ++round) {
            const int nL = lCntArr[round];            // stable post-barrier
            if (nL == 0) break;
            const u16* inL = lList2 + (round & 1) * CAP;
            u16* outL = lList2 + ((round + 1) & 1) * CAP;
            int* outC = lCntArr + (round + 1);        // pre-zeroed
            for (int base = wave * 2; base < nL; base += 32) {
                const int li = base + h;
                const bool act = (li < nL);
                const int slot = act ? (int)inL[li] : 0;
                const u64 myEnc = (1ull << 63) | (u64)slot;
                u64 w = (act && sub < NW) ? col[slot * NW + sub] : 0ull;
                int low = act ? (int)curLow[slot] : 0xFFFE;
                bool done = !act || (low == 0xFFFE);
                while (__ballot(!done) != 0ull) {
                    u64 o = (!done) ? *(volatile u64*)&ownerBnd[low] : 0ull;
                    bool wantChase = !done && (o < myEnc);
                    bool wantClaim = !done && !wantChase;
                    if (wantChase) xorOwnerH(o, w, sub, col);
                    if (__ballot(wantClaim) != 0ull) {
                        if (wantClaim && sub < NW) col[slot * NW + sub] = w;
                        __threadfence_block();
                        u64 got = 0;
                        if (wantClaim && sub == 0) {
                            u64 cur = *(volatile u64*)&ownerBnd[low];
                            while (myEnc < cur) {
                                u64 prev = atomicCAS(&ownerBnd[low], cur, myEnc);
                                if (prev == cur) {
                                    if (cur != ~0ull) {        // evicted settled col
                                        int ix = atomicAdd(outC, 1);
                                        outL[ix] = (u16)(cur & 0xFFFFull);
                                    }
                                    break;
                                }
                                cur = prev;
                            }
                            got = cur;
                        }
                        // broadcast got within each half (src lane h*32)
                        u32 glo = (u32)__shfl((int)(u32)got, h * 32, 64);
                        u32 ghi = (u32)__shfl((int)(u32)(got >> 32), h * 32, 64);
                        got = ((u64)ghi << 32) | glo;
                        if (wantClaim) {
                            if (got < myEnc) {       // raced & lost: reduce through
                                xorOwnerH(got, w, sub, col);
                                wantChase = true;
                            } else {
                                done = true;         // rested
                            }
                        }
                    }
                    // per-half low rescan for halves that XORed this iteration
                    u64 full = __ballot(w != 0ull);
                    if (wantChase) {
                        u32 mh = (u32)(full >> (h * 32));
                        if (mh == 0u) { low = 0xFFFE; done = true; }
                        else {
                            int L = 31 - __builtin_clz(mh);
                            int cnd = (sub << 6) + 63 - __builtin_clzll(w | 1ull);
                            low = __shfl(cnd, h * 32 + L, 64);
                        }
                    }
                }
                if (act) {
                    if (sub == 0) curLow[slot] = (u16)low;
                    if (sub < NW) col[slot * NW + sub] = w;
                }
            }
            __syncthreads();
        }
    }
    // publish pairs for non-apparent squares
    if (tid < M) {
        u16 cl = curLow[tid];
        pairLow[nonapp[tid]] = (cl == 0xFFFEu) ? (u16)0xFFFDu : cl;
    }
    __syncthreads();

    // ---- P5+P6+P7 fused: packed keys + exact 64-wide tournament (3 barriers) ----
    // key = ~((f64_bits(pr) & ~0xFFF) | j): distinct pr (f32 differences) are
    // >=2^27 d-ulps apart, so low 12 bits carry j; ascending = descending
    // (pr, j) = argsort(pers)[::-1]. 12 chunks of 64 -> sort64 each -> merge
    // tree 12->6->3->1 keeping exact smallest-64 at every level.
    {
        if (wave < 12) {
            int i = wave * 64 + lane;
            u64 key = ~0ull;
            if (i < NSQ) {
                int pl = (int)pairLow[i];
                if (pl != 0xFFFD && pl != 0xFFFF) {
                    int low = pl & 0x7FFF;
                    double pr = (double)sqF[i] - (double)edgeFr[low];
                    if (pr > 0.0) {
                        u64 bits = (u64)__double_as_longlong(pr);
                        key = ~((bits & ~0xFFFull) | (u64)(u32)i);
                    }
                }
            }
            candA[wave * 64 + lane] = sort64(key, lane);
        }
        __syncthreads();
        if (wave < 6) {
            u64 a = candA[(2 * wave) * 64 + lane];
            u64 b = candA[(2 * wave + 1) * 64 + lane];
            candB[wave * 64 + lane] = merge64(a, b, lane);
        }
        __syncthreads();
        if (wave < 3) {
            u64 a = candB[(2 * wave) * 64 + lane];
            u64 b = candB[(2 * wave + 1) * 64 + lane];
            candA[wave * 64 + lane] = merge64(a, b, lane);
        }
        __syncthreads();
        if (wave == 0) {
            u64 a = candA[lane], b = candA[64 + lane], c = candA[128 + lane];
            u64 f = merge64(merge64(a, b, lane), c, lane);
            if (lane < CARD) {
                float bv, dv;
                if (f != ~0ull) {
                    u64 kb = ~f;
                    int j = (int)(kb & 0xFFFull);
                    int low = (int)pairLow[j] & 0x7FFF;
                    bv = edgeFr[low];
                    dv = sqF[j];
                } else {
                    bv = *padvP; dv = *padvP;    // pad rows -> Ip[0,0]
                }
                out[2 * lane]     = bv;
                out[2 * lane + 1] = dv;
            }
        }
    }
}

extern "C" void kernel_launch(void* const* d_in, const int* in_sizes, int n_in,
                              void* d_out, int out_size, void* d_ws, size_t ws_size,
                              hipStream_t stream) {
    const float* I = (const float*)d_in[0];   // [28,28,2] float32
    const float* p = (const float*)d_in[1];   // [2,1] float32
    float* out = (float*)d_out;               // [50,2] float32 flat
    hipLaunchKernelGGL(cubical_kernel, dim3(1), dim3(BS), 0, stream, I, p, out);
}

// Round 13
// 99.504 us; speedup vs baseline: 1.0524x; 1.0450x over previous
//
#include <hip/hip_runtime.h>

// 28x28 image, dim-1 persistence, card 50
#define IMG_H 28
#define IMG_W 28
#define AA 55            // 2*H-1
#define NCELL 3025       // 55*55
#define NEDGE 1512
#define NSQ 729
#define CARD 50
#define NW 24            // 1512 bits -> 24 u64 words
#define CAP 160          // LDS-resident columns (measured M <= 160 on this input)
#define BS 1024

typedef unsigned long long u64;
typedef unsigned int u32;
typedef unsigned short u16;

// ---- shared memory layout (manual union; all aliases time-disjoint) ----
#define OFF_KEYSE   0        // u64[2048] 16384          (P0-P3b)
#define OFF_KEYSS   16384    // u64[1024]  8192          (P0-P3b)
#define OFF_IP      24576    // f32[784]   3136          (P0-P1)
#define OFF_RANKE   27712    // u16[1512]  3024          (P3-P3b)
#define OFF_RANKSQ  30736    // u16[729]   1458 ->32194  (P3-P3b)
#define OFF_COL     0        // u64[CAP*24] 30720        (P4b-P4c; aliases dead keys)
#define OFF_OWNB    30720    // u64[1536] 12288 ->43008  (P4a-P4c; aliases dead ranks)
#define OFF_CANDA   0        // u64[768]   6144          (P6; aliases dead col)
#define OFF_CANDB   8192     // u64[192]   1536          (P6)
#define OFF_BND     43008    // u64[729]   5832          (P3b-P4b)
#define OFF_EDGEF   48840    // f32[1512]  6048          (P3+)
#define OFF_SQF     54888    // f32[729]   2916 ->57804  (P3+)
#define OFF_LLIST2  57808    // u16[2*CAP]  640 ->58448  (P4)
#define OFF_CURLOW  58448    // u16[CAP]    320 ->58768  (P4)
#define OFF_LCNT    58768    // int[256]   1024 ->59792  (P4)
#define OFF_PAIRLOW 60832    // u16[729]   1458          (P3b+)
#define OFF_NONAPP  62296    // u16[736]   1472          (P4a+)
#define OFF_SCAL    63768    // float padv; int M
#define SMEM_TOTAL  63776

__device__ __forceinline__ int edgeCid(int a, int b) {
    // (a+b) odd: a odd -> [0,756); a even -> [756,1512)
    return (a & 1) ? (((a - 1) >> 1) * 28 + (b >> 1))
                   : (756 + (a >> 1) * 27 + ((b - 1) >> 1));
}

__device__ __forceinline__ u32 sortable(float f) {
    u32 fb = __float_as_uint(f);
    return (fb & 0x80000000u) ? ~fb : (fb | 0x80000000u);
}
__device__ __forceinline__ float unsortable(u32 v) {
    return __uint_as_float((v & 0x80000000u) ? (v & 0x7FFFFFFFu) : ~v);
}

__device__ __forceinline__ u64 shflx64(u64 v, int s) {
    u32 lo = __shfl_xor((u32)v, s, 64);
    u32 hi = __shfl_xor((u32)(v >> 32), s, 64);
    return ((u64)hi << 32) | lo;
}

__device__ __forceinline__ void cswapDir(u64& a, u64& b, bool up) {
    u64 mn = a < b ? a : b, mx = a < b ? b : a;
    a = up ? mn : mx; b = up ? mx : mn;
}

// one cross-lane bitonic stage (stride s<64) on register v at element index i
__device__ __forceinline__ u64 bstage(u64 v, int i, int s, int size) {
    u64 p = shflx64(v, s);
    bool keepmin = (((i & size) == 0) == ((i & s) == 0));
    return keepmin ? (v < p ? v : p) : (v > p ? v : p);
}

// session A: sizes 2..64, all strides, on a 128-chunk (r0@i0, r1@i0+64)
__device__ __forceinline__ void sessA(u64& r0, u64& r1, int i0) {
    for (int size = 2; size <= 64; size <<= 1)
        for (int s = size >> 1; s; s >>= 1) {
            r0 = bstage(r0, i0, s, size);
            r1 = bstage(r1, i0 + 64, s, size);
        }
}
// session B: one size>=128, strides 64..1 (asc uniform over the chunk)
__device__ __forceinline__ void sessB(u64& r0, u64& r1, int i0, int size) {
    bool asc = ((i0 & size) == 0);
    { u64 mn = r0 < r1 ? r0 : r1, mx = r0 < r1 ? r1 : r0;
      r0 = asc ? mn : mx; r1 = asc ? mx : mn; }
    for (int s = 32; s; s >>= 1) {
        bool keep = (asc == ((i0 & s) == 0));
        u64 p0 = shflx64(r0, s);
        r0 = keep ? (r0 < p0 ? r0 : p0) : (r0 > p0 ? r0 : p0);
        u64 p1 = shflx64(r1, s);
        r1 = keep ? (r1 < p1 ? r1 : p1) : (r1 > p1 ? r1 : p1);
    }
}

// Fused classic cascade for one size pass S = G*128: all strides S/2..128 on
// G-element groups held in registers. Group gid: high = gid>>7, low = gid&127;
// element(g) = (high*G + g)*128 + low; direction uniform: up = ((high&1)==0).
template<int G>
__device__ __forceinline__ void fusedClassicArr(u64* arr, int nElem) {
    const int nG = nElem / G;
    for (int gid = (int)threadIdx.x; gid < nG; gid += BS) {
        int high = gid >> 7, low = gid & 127;
        bool up = ((high & 1) == 0);
        int base = high * G * 128 + low;
        u64 k[G];
        #pragma unroll
        for (int g = 0; g < G; ++g) k[g] = arr[base + g * 128];
        #pragma unroll
        for (int d = G / 2; d >= 1; d >>= 1)
            #pragma unroll
            for (int g = 0; g < G; ++g)
                if (!(g & d)) cswapDir(k[g], k[g | d], up);
        #pragma unroll
        for (int g = 0; g < G; ++g) arr[base + g * 128] = k[g];
    }
}

// sessB window over edges (and squares if hasS) for one size
__device__ __forceinline__ void sessWin(u64* kE, u64* kS, int i0, int size, bool hasS) {
    u64 a = kE[i0], b = kE[i0 + 64];
    sessB(a, b, i0, size);
    kE[i0] = a; kE[i0 + 64] = b;
    if (hasS) {
        u64 c = kS[i0], d = kS[i0 + 64];
        sessB(c, d, i0, size);
        kS[i0] = c; kS[i0 + 64] = d;
    }
}

// generic lane-indexed stage for the P6 helpers
__device__ __forceinline__ u64 lstage(u64 v, int lane, int s, bool up) {
    u64 p = shflx64(v, s);
    bool keepmin = (up == ((lane & s) == 0));
    return keepmin ? (v < p ? v : p) : (v > p ? v : p);
}

// full ascending bitonic sort of 64 elements (1 reg/lane), loop-coded
__device__ __forceinline__ u64 sort64(u64 v, int lane) {
    for (int size = 2; size <= 32; size <<= 1)
        for (int s = size >> 1; s; s >>= 1)
            v = lstage(v, lane, s, (lane & size) == 0);
    for (int s = 32; s; s >>= 1)
        v = lstage(v, lane, s, true);
    return v;
}
// merge two ascending 64-lists, keep smallest 64 (exact), ascending result
__device__ __forceinline__ u64 merge64(u64 a, u64 b, int lane) {
    u64 br = shflx64(b, 63);            // reverse
    u64 m = a < br ? a : br;            // bitonic lower half
    for (int s = 32; s; s >>= 1)
        m = lstage(m, lane, s, true);
    return m;
}

// XOR the owner's column into w. bit63=0 -> apparent (4x12-bit edge ranks
// inline); bit63=1 -> settled column slot.
__device__ __forceinline__ void xorOwner(u64 o, u64& w, int lane, const u64* col) {
    if (!(o >> 63)) {
        #pragma unroll
        for (int q = 0; q < 4; ++q) {
            int rr = (int)((o >> (12 * q)) & 0xFFFull);
            if ((rr >> 6) == lane) w ^= 1ull << (rr & 63);
        }
    } else {
        int s = (int)(o & 0xFFFFull);
        if (lane < NW) w ^= col[s * NW + lane];
    }
}

// highest set bit position across the wave's 64xu64 bitset (lane i = word i)
__device__ __forceinline__ int findLow(u64 w, int lane) {
    u64 mask = __ballot(w != 0ull);
    if (mask == 0ull) return 0xFFFE;                 // dead
    int L = 63 - __builtin_clzll(mask);
    int cand = (lane << 6) + 63 - __builtin_clzll(w | 1ull);  // valid where w!=0
    return __builtin_amdgcn_readlane(cand, L);
}

__global__ __launch_bounds__(BS) void cubical_kernel(const float* __restrict__ I,
                                                     const float* __restrict__ p,
                                                     float* __restrict__ out) {
    __shared__ __align__(16) char smem[SMEM_TOTAL];
    u64*    keysE   = (u64*)(smem + OFF_KEYSE);
    u64*    keysS   = (u64*)(smem + OFF_KEYSS);
    float*  Ip      = (float*)(smem + OFF_IP);
    u16*    rankE   = (u16*)(smem + OFF_RANKE);
    u16*    rankSq  = (u16*)(smem + OFF_RANKSQ);
    u64*    col     = (u64*)(smem + OFF_COL);      // [CAP][NW]
    u64*    ownerBnd= (u64*)(smem + OFF_OWNB);     // [1536]
    u64*    candA   = (u64*)(smem + OFF_CANDA);    // [768]
    u64*    candB   = (u64*)(smem + OFF_CANDB);    // [192]
    u64*    bnd     = (u64*)(smem + OFF_BND);
    float*  edgeFr  = (float*)(smem + OFF_EDGEF);
    float*  sqF     = (float*)(smem + OFF_SQF);
    u16*    lList2  = (u16*)(smem + OFF_LLIST2);   // [2][CAP]
    u16*    curLow  = (u16*)(smem + OFF_CURLOW);
    int*    lCntArr = (int*)(smem + OFF_LCNT);     // [256]
    u16*    pairLow = (u16*)(smem + OFF_PAIRLOW);
    u16*    nonapp  = (u16*)(smem + OFF_NONAPP);
    float*  padvP   = (float*)(smem + OFF_SCAL);
    int*    Mp      = (int*)(smem + OFF_SCAL + 4);

    const int tid = threadIdx.x;
    const int wave = tid >> 6, lane = tid & 63;

    // ---- P0: Ip = I.p ; pads ----
    const float p0 = p[0], p1 = p[1];
    for (int i = tid; i < IMG_H * IMG_W; i += BS) {
        float v = I[2 * i] * p0 + I[2 * i + 1] * p1;
        Ip[i] = v;
        if (i == 0) *padvP = v;
    }
    for (int i = 1512 + tid; i < 2048; i += BS) keysE[i] = ~0ull;
    for (int i = 729 + tid; i < 1024; i += BS) keysS[i] = ~0ull;
    __syncthreads();

    // ---- P1: F + sort keys for edges & squares ----
    for (int idx = tid; idx < NCELL; idx += BS) {
        int a = idx / AA, b = idx % AA;
        int da = a & 1, db = b & 1;
        int dim = da + db;
        if (dim == 0) continue;
        int r0, r1, c0, c1;
        if (da) { r0 = r1 = (a - 1) >> 1; }
        else    { r1 = a >> 1; r0 = (a == 0) ? r1 : r1 - 1; }
        if (db) { c0 = c1 = (b - 1) >> 1; }
        else    { c1 = b >> 1; c0 = (b == 0) ? c1 : c1 - 1; }
        float best = Ip[r0 * IMG_W + c0];
        best = fminf(best, Ip[r0 * IMG_W + c1]);
        best = fminf(best, Ip[r1 * IMG_W + c0]);
        best = fminf(best, Ip[r1 * IMG_W + c1]);
        u64 key = ((u64)sortable(best) << 12) | (u32)idx;
        if (dim == 1) keysE[edgeCid(a, b)] = key;
        else          keysS[((a - 1) >> 1) * 27 + ((b - 1) >> 1)] = key;
    }
    __syncthreads();

    // ---- P2: bitonic sorts, 9 barriers. Window 0: sizes 2..128 fully
    // in-register per 128-chunk (sessA+sessB fused — R9 paid an extra
    // store/barrier/load here). Then per size S=256..2048: ONE fused
    // register window for all strides >=128 (G=S/128 elems/thread,
    // direction uniform per group) + one sessB window for strides <=64.
    {
        const int eB = wave * 128 + lane;      // 16 waves cover 2048 edges
        const bool hasS = (wave < 8);          // waves 0-7 cover 1024 squares
        {
            u64 a = keysE[eB], b = keysE[eB + 64];
            sessA(a, b, eB);
            sessB(a, b, eB, 128);
            keysE[eB] = a; keysE[eB + 64] = b;
            if (hasS) {
                u64 c = keysS[eB], d = keysS[eB + 64];
                sessA(c, d, eB);
                sessB(c, d, eB, 128);
                keysS[eB] = c; keysS[eB + 64] = d;
            }
        }
        __syncthreads();
        // S = 256
        fusedClassicArr<2>(keysE, 2048);
        fusedClassicArr<2>(keysS, 1024);
        __syncthreads();
        sessWin(keysE, keysS, eB, 256, hasS);
        __syncthreads();
        // S = 512
        fusedClassicArr<4>(keysE, 2048);
        fusedClassicArr<4>(keysS, 1024);
        __syncthreads();
        sessWin(keysE, keysS, eB, 512, hasS);
        __syncthreads();
        // S = 1024
        fusedClassicArr<8>(keysE, 2048);
        fusedClassicArr<8>(keysS, 1024);
        __syncthreads();
        sessWin(keysE, keysS, eB, 1024, hasS);   // squares FINAL
        __syncthreads();
        // S = 2048 (edges only)
        fusedClassicArr<16>(keysE, 2048);
        __syncthreads();
        sessWin(keysE, keysS, eB, 2048, false);  // edges FINAL
        __syncthreads();
    }

    // ---- P3: rank lookups + F-by-rank ----
    for (int r = tid; r < NEDGE; r += BS) {
        u64 k = keysE[r];
        int idx = (int)(k & 0xFFFull);
        int a = idx / AA, b = idx % AA;
        rankE[edgeCid(a, b)] = (u16)r;
        edgeFr[r] = unsortable((u32)(k >> 12));
    }
    for (int r = tid; r < NSQ; r += BS) {
        u64 k = keysS[r];
        int idx = (int)(k & 0xFFFull);
        int a = idx / AA, b = idx % AA;
        rankSq[((a - 1) >> 1) * 27 + ((b - 1) >> 1)] = (u16)r;
        sqF[r] = unsortable((u32)(k >> 12));
    }
    __syncthreads();

    // ---- P3b: boundary ranks + apparent-pair detection ----
    // pairLow: apparent -> 0x8000|low ; pending -> 0xFFFF.
    for (int j = tid; j < NSQ; j += BS) {
        int sidx = (int)(keysS[j] & 0xFFFull);
        int a = sidx / AA, b = sidx % AA;          // both odd
        int ec[4] = { sidx - AA, sidx + AA, sidx - 1, sidx + 1 };
        int er[4];
        er[0] = rankE[edgeCid(a - 1, b)];
        er[1] = rankE[edgeCid(a + 1, b)];
        er[2] = rankE[edgeCid(a, b - 1)];
        er[3] = rankE[edgeCid(a, b + 1)];
        bnd[j] = (u64)er[0] | ((u64)er[1] << 16) | ((u64)er[2] << 32) | ((u64)er[3] << 48);
        int bq = 0;
        if (er[1] > er[bq]) bq = 1;
        if (er[2] > er[bq]) bq = 2;
        if (er[3] > er[bq]) bq = 3;
        int ecell = ec[bq];
        int x = ecell / AA, y = ecell % AA;
        u32 rmin = 0xFFFFFFFFu;
        if (x & 1) {
            if (y >= 2)  rmin = rankSq[((x - 1) >> 1) * 27 + ((y - 2) >> 1)];
            if (y <= 52) { u32 r2 = rankSq[((x - 1) >> 1) * 27 + (y >> 1)]; rmin = min(rmin, r2); }
        } else {
            if (x >= 2)  rmin = rankSq[((x - 2) >> 1) * 27 + ((y - 1) >> 1)];
            if (x <= 52) { u32 r2 = rankSq[(x >> 1) * 27 + ((y - 1) >> 1)]; rmin = min(rmin, r2); }
        }
        pairLow[j] = (rmin == (u32)j) ? (u16)(0x8000u | er[bq]) : (u16)0xFFFFu;
    }
    __syncthreads();   // keys/rank region dead from here

    // ---- P4a: fused owner table init + apparent installs + compact pending ----
    for (int i = tid; i < 1536; i += BS) ownerBnd[i] = ~0ull;
    __syncthreads();
    for (int j = tid; j < NSQ; j += BS) {
        u16 pl = pairLow[j];
        if (pl != 0xFFFFu) {
            u64 bd = bnd[j];
            u64 e = (bd & 0xFFFull) | (((bd >> 16) & 0xFFFull) << 12)
                  | (((bd >> 32) & 0xFFFull) << 24) | (((bd >> 48) & 0xFFFull) << 36);
            ownerBnd[pl & 0x7FFF] = e;   // unique per low; bit63=0 < settled encs
        }
    }
    if (tid < 64) {
        int cnt = 0;
        for (int base = 0; base < NSQ; base += 64) {
            int j = base + lane;
            bool f = (j < NSQ) && (pairLow[j] == 0xFFFFu);
            u64 m = __ballot(f);
            int pfx = __popcll(m & ((1ull << lane) - 1ull));
            if (f) nonapp[cnt + pfx] = (u16)j;
            cnt += __popcll(m);
        }
        if (lane == 0) *Mp = (cnt > CAP) ? CAP : cnt;
    }
    __syncthreads();
    const int M = *Mp;

    // ---- P4b: init columns + lows + round-0 work list + per-round counters ----
    for (int idx = tid; idx < M * NW; idx += BS) {
        int slot = idx / NW, w = idx - slot * NW;
        u64 bd = bnd[nonapp[slot]];
        u64 x = 0ull;
        #pragma unroll
        for (int q = 0; q < 4; ++q) {
            int rr = (int)((bd >> (16 * q)) & 0xFFFFull);
            if ((rr >> 6) == w) x ^= 1ull << (rr & 63);
        }
        col[idx] = x;
    }
    if (tid < 256) lCntArr[tid] = 0;
    if (tid < M) {
        u64 bd = bnd[nonapp[tid]];
        int mx = 0;
        #pragma unroll
        for (int q = 0; q < 4; ++q) {
            int rr = (int)((bd >> (16 * q)) & 0xFFFFull);
            if (rr > mx) mx = rr;
        }
        curLow[tid] = (u16)mx;
        lList2[tid] = (u16)tid;
    }
    if (tid == 0) lCntArr[0] = M;
    __syncthreads();

    // ---- P4c: single-chase chase-and-claim, 1 barrier/round (R9-verified;
    // dual-chase regressed, R11 — lockstep coupling). Smaller-into-larger
    // only: at low L with owner o < myEnc, XOR through and keep chasing; at
    // o >= myEnc: publish col, fence, CAS-min claim (evictor appends any
    // displaced settled victim to the next round's list). Race-losers XOR
    // through the new smaller owner inline.
    {
        const int nWaves = BS / 64;
        for (int round = 0; round < 255; ++round) {
            const int nL = lCntArr[round];            // stable post-barrier
            if (nL == 0) break;
            const u16* inL = lList2 + (round & 1) * CAP;
            u16* outL = lList2 + ((round + 1) & 1) * CAP;
            int* outC = lCntArr + (round + 1);        // pre-zeroed
            for (int li = wave; li < nL; li += nWaves) {
                int slot = (int)inL[li];
                const u64 myEnc = (1ull << 63) | (u64)slot;
                u64 w = (lane < NW) ? col[slot * NW + lane] : 0ull;
                int low = (int)curLow[slot];
                while (low != 0xFFFE) {
                    u64 o = *(volatile u64*)&ownerBnd[low];
                    if (o < myEnc) {
                        xorOwner(o, w, lane, col);
                        low = findLow(w, lane);
                    } else {
                        if (lane < NW) col[slot * NW + lane] = w;
                        __threadfence_block();
                        u64 got = 0;
                        if (lane == 0) {
                            u64 cur = *(volatile u64*)&ownerBnd[low];
                            while (myEnc < cur) {
                                u64 prev = atomicCAS(&ownerBnd[low], cur, myEnc);
                                if (prev == cur) {
                                    if (cur != ~0ull) {        // evicted settled col
                                        int ix = atomicAdd(outC, 1);
                                        outL[ix] = (u16)(cur & 0xFFFFull);
                                    }
                                    break;
                                }
                                cur = prev;
                            }
                            got = cur;
                        }
                        u32 glo = __builtin_amdgcn_readlane((u32)got, 0);
                        u32 ghi = __builtin_amdgcn_readlane((u32)(got >> 32), 0);
                        got = ((u64)ghi << 32) | glo;
                        if (got < myEnc) {           // raced & lost: reduce through
                            xorOwner(got, w, lane, col);
                            low = findLow(w, lane);
                        } else break;                // rested
                    }
                }
                if (lane == 0) curLow[slot] = (u16)low;
                if (lane < NW) col[slot * NW + lane] = w;
            }
            __syncthreads();
        }
    }
    // publish pairs for non-apparent squares
    if (tid < M) {
        u16 cl = curLow[tid];
        pairLow[nonapp[tid]] = (cl == 0xFFFEu) ? (u16)0xFFFDu : cl;
    }
    __syncthreads();

    // ---- P5+P6+P7 fused: packed keys + exact 64-wide tournament (3 barriers) ----
    // key = ~((f64_bits(pr) & ~0xFFF) | j): distinct pr (f32 differences) are
    // >=2^27 d-ulps apart, so low 12 bits carry j; ascending = descending
    // (pr, j) = argsort(pers)[::-1]. 12 chunks of 64 -> sort64 each -> merge
    // tree 12->6->3->1 keeping exact smallest-64 at every level.
    {
        if (wave < 12) {
            int i = wave * 64 + lane;
            u64 key = ~0ull;
            if (i < NSQ) {
                int pl = (int)pairLow[i];
                if (pl != 0xFFFD && pl != 0xFFFF) {
                    int low = pl & 0x7FFF;
                    double pr = (double)sqF[i] - (double)edgeFr[low];
                    if (pr > 0.0) {
                        u64 bits = (u64)__double_as_longlong(pr);
                        key = ~((bits & ~0xFFFull) | (u64)(u32)i);
                    }
                }
            }
            candA[wave * 64 + lane] = sort64(key, lane);
        }
        __syncthreads();
        if (wave < 6) {
            u64 a = candA[(2 * wave) * 64 + lane];
            u64 b = candA[(2 * wave + 1) * 64 + lane];
            candB[wave * 64 + lane] = merge64(a, b, lane);
        }
        __syncthreads();
        if (wave < 3) {
            u64 a = candB[(2 * wave) * 64 + lane];
            u64 b = candB[(2 * wave + 1) * 64 + lane];
            candA[wave * 64 + lane] = merge64(a, b, lane);
        }
        __syncthreads();
        if (wave == 0) {
            u64 a = candA[lane], b = candA[64 + lane], c = candA[128 + lane];
            u64 f = merge64(merge64(a, b, lane), c, lane);
            if (lane < CARD) {
                float bv, dv;
                if (f != ~0ull) {
                    u64 kb = ~f;
                    int j = (int)(kb & 0xFFFull);
                    int low = (int)pairLow[j] & 0x7FFF;
                    bv = edgeFr[low];
                    dv = sqF[j];
                } else {
                    bv = *padvP; dv = *padvP;    // pad rows -> Ip[0,0]
                }
                out[2 * lane]     = bv;
                out[2 * lane + 1] = dv;
            }
        }
    }
}

extern "C" void kernel_launch(void* const* d_in, const int* in_sizes, int n_in,
                              void* d_out, int out_size, void* d_ws, size_t ws_size,
                              hipStream_t stream) {
    const float* I = (const float*)d_in[0];   // [28,28,2] float32
    const float* p = (const float*)d_in[1];   // [2,1] float32
    float* out = (float*)d_out;               // [50,2] float32 flat
    hipLaunchKernelGGL(cubical_kernel, dim3(1), dim3(BS), 0, stream, I, p, out);
}